// Round 1
// baseline (170.784 us; speedup 1.0000x reference)
//
#include <hip/hip_runtime.h>

#define B_DIM   4096
#define IN_DIM  4096
#define OUT_DIM 4096

// One block per row (256 threads). Blocks [0, B_DIM): input rows ->
// ws[b] = sum_i input[b,i]. Blocks [B_DIM, B_DIM+OUT_DIM): weight rows ->
// ws[B_DIM + o] = bias[o] * sum_i weight[o,i]  (pre-multiplied so the
// epilogue is a single FMA per element).
__global__ __launch_bounds__(256) void rowsum_kernel(
    const float* __restrict__ input, const float* __restrict__ weight,
    const float* __restrict__ bias, float* __restrict__ ws)
{
    const int row = blockIdx.x;
    const float* src = (row < B_DIM)
        ? input  + (size_t)row * IN_DIM
        : weight + (size_t)(row - B_DIM) * IN_DIM;

    const float4* src4 = (const float4*)src;   // 1024 float4 per row
    const int t = threadIdx.x;

    float s = 0.f;
    #pragma unroll
    for (int i = 0; i < 4; ++i) {              // 4 coalesced float4 per lane
        float4 v = src4[t + i * 256];
        s += (v.x + v.y) + (v.z + v.w);
    }

    // wave (64-lane) shuffle reduction
    #pragma unroll
    for (int off = 32; off > 0; off >>= 1)
        s += __shfl_down(s, off, 64);

    __shared__ float smem[4];
    const int wave = t >> 6;
    if ((t & 63) == 0) smem[wave] = s;
    __syncthreads();

    if (t == 0) {
        float tot = (smem[0] + smem[1]) + (smem[2] + smem[3]);
        if (row < B_DIM) {
            ws[row] = tot;
        } else {
            const int o = row - B_DIM;
            ws[B_DIM + o] = tot * bias[o];
        }
    }
}

// out[b, o] = x_sum[b] * bias[o] + wb[o], vectorized as float4.
// idx indexes float4s: b = idx / (OUT_DIM/4), o4 = idx % (OUT_DIM/4).
// bias / wb (16 KB each) are L1-resident broadcast reads; x_sum[b] is
// wave-uniform (1024 float4 per row = 16 waves per row, same b per wave).
__global__ __launch_bounds__(256) void epilogue_kernel(
    const float* __restrict__ bias, const float* __restrict__ ws,
    float* __restrict__ out)
{
    const int idx = blockIdx.x * 256 + threadIdx.x;
    const int b  = idx >> 10;          // OUT_DIM/4 = 1024
    const int o4 = idx & 1023;

    const float  xs = ws[b];
    const float4 bi = ((const float4*)bias)[o4];
    const float4 wb = ((const float4*)(ws + B_DIM))[o4];

    float4 r;
    r.x = fmaf(xs, bi.x, wb.x);
    r.y = fmaf(xs, bi.y, wb.y);
    r.z = fmaf(xs, bi.z, wb.z);
    r.w = fmaf(xs, bi.w, wb.w);

    ((float4*)out)[idx] = r;
}

extern "C" void kernel_launch(void* const* d_in, const int* in_sizes, int n_in,
                              void* d_out, int out_size, void* d_ws, size_t ws_size,
                              hipStream_t stream) {
    const float* input  = (const float*)d_in[0];
    const float* weight = (const float*)d_in[1];
    const float* bias   = (const float*)d_in[2];
    float* out = (float*)d_out;
    float* ws  = (float*)d_ws;   // [0, B_DIM): x_sum; [B_DIM, B_DIM+OUT_DIM): bias*w_sum

    rowsum_kernel<<<B_DIM + OUT_DIM, 256, 0, stream>>>(input, weight, bias, ws);

    const int n_f4 = B_DIM * (OUT_DIM / 4);          // 4M float4
    epilogue_kernel<<<n_f4 / 256, 256, 0, stream>>>(bias, ws, out);
}